// Round 3
// baseline (160.468 us; speedup 1.0000x reference)
//
#include <hip/hip_runtime.h>
#include <hip/hip_bf16.h>
#include <stdint.h>

typedef unsigned short u16;
typedef unsigned int u32;
typedef __attribute__((ext_vector_type(8))) short short8;
typedef __attribute__((ext_vector_type(4))) float f32x4;
typedef __attribute__((ext_vector_type(4))) unsigned int u32x4;
typedef __attribute__((ext_vector_type(4))) unsigned short u16x4;

#define MFMA16(a, b, c) __builtin_amdgcn_mfma_f32_16x16x32_bf16((a), (b), (c), 0, 0, 0)

__device__ __forceinline__ u16 f2bf(float f) {
    union { float f; uint32_t u; } v; v.f = f;
    return (u16)((v.u + 0x7FFFu + ((v.u >> 16) & 1u)) >> 16);
}

// async global -> LDS, 16 bytes per lane
__device__ __forceinline__ void gl_lds16(const u16* g, u16* l) {
    __builtin_amdgcn_global_load_lds(
        (const __attribute__((address_space(1))) u32*)g,
        (__attribute__((address_space(3))) u32*)l,
        16, 0, 0);
}

// ---------------- convert kernels ----------------

__global__ __launch_bounds__(256) void k_cvt_x(const float* __restrict__ in,
                                               u16* __restrict__ out, int n) {
    int i = (blockIdx.x * 256 + threadIdx.x) * 4;
    if (i >= n) return;
    f32x4 v = *(const f32x4*)(in + i);
    u16x4 o;
    o[0] = f2bf(v[0]); o[1] = f2bf(v[1]); o[2] = f2bf(v[2]); o[3] = f2bf(v[3]);
    *(u16x4*)(out + i) = o;
}

// LDS-tiled transpose+convert: out[n*K+k] = bf16(in[k*N+n]); K,N multiples of 64
__global__ __launch_bounds__(256) void k_cvt_T(const float* __restrict__ in,
                                               u16* __restrict__ out, int K, int N) {
    __shared__ u16 t[64][72];
    const int kb = blockIdx.y * 64, nb = blockIdx.x * 64;
    const int tid = threadIdx.x;
    const int r = tid >> 4, c4 = (tid & 15) << 2;
#pragma unroll
    for (int p = 0; p < 4; ++p) {
        int k = r + p * 16;
        f32x4 v = *(const f32x4*)&in[(size_t)(kb + k) * N + nb + c4];
#pragma unroll
        for (int q = 0; q < 4; ++q) t[c4 + q][k] = f2bf(v[q]);
    }
    __syncthreads();
#pragma unroll
    for (int p = 0; p < 4; ++p) {
        int nn = r + p * 16;
        u16x4 o;
#pragma unroll
        for (int q = 0; q < 4; ++q) o[q] = t[nn][c4 + q];
        *(u16x4*)&out[(size_t)(nb + nn) * K + kb + c4] = o;
    }
}

// ---------------- GEMM1: 256x256 8-phase pipelined (m201-style template) ----------------
// A [8192][768], BT [2304][768]; scatter Q/K [BH][T][96], V^T [BH][96][1024]
// LDS (u16): A halves at (2*buf+kk)*8192, B halves at 32768 + (2*buf+kk)*8192 ; 128 KiB total
// half-tile = one matrix x one K-half (256 rows x 32 k), staged as 2 gl_lds16/thread
// swizzle: element idx = row*32 + 8*(g ^ ((lr>>1)&3))  (involution, 2-way max bank aliasing)

#define PHASE(BUF, KK, MH, LOADB, DOSTAGE, SRC, STREG, STBUF, STKK, STTILE, VMC) do {          \
    const u16* Ab_ = &lds[(2*(BUF)+(KK)) * 8192];                                              \
    const u16* Bb_ = &lds[32768 + (2*(BUF)+(KK)) * 8192];                                      \
    short8 af_[4];                                                                             \
    _Pragma("unroll") for (int ii = 0; ii < 4; ++ii)                                           \
        af_[ii] = *(const short8*)&Ab_[(128*wr + 16*(4*(MH)+ii) + lr) * 32 + gsw];             \
    if (LOADB) {                                                                               \
        _Pragma("unroll") for (int jj = 0; jj < 4; ++jj)                                       \
            bfr[jj] = *(const short8*)&Bb_[(64*wc + 16*jj + lr) * 32 + gsw];                   \
    }                                                                                          \
    if (DOSTAGE) {                                                                             \
        u16* dst_ = &lds[(STREG) + (2*(STBUF)+(STKK)) * 8192];                                 \
        _Pragma("unroll") for (int h2 = 0; h2 < 2; ++h2) {                                     \
            int c_ = tid + h2 * 512;                                                           \
            int u_ = c_ ^ ((c_ >> 3) & 3);                                                     \
            gl_lds16(&(SRC)[(size_t)(u_ >> 2) * 768 + (STTILE)*64 + (STKK)*32 + (u_ & 3)*8],   \
                     &dst_[c_ * 8]);                                                           \
        }                                                                                      \
    }                                                                                          \
    __builtin_amdgcn_sched_barrier(0);                                                         \
    __builtin_amdgcn_s_barrier();                                                              \
    asm volatile("s_waitcnt lgkmcnt(0)" ::: "memory");                                         \
    __builtin_amdgcn_sched_barrier(0);                                                         \
    __builtin_amdgcn_s_setprio(1);                                                             \
    _Pragma("unroll") for (int ii = 0; ii < 4; ++ii)                                           \
        _Pragma("unroll") for (int jj = 0; jj < 4; ++jj)                                       \
            acc[4*(MH)+ii][jj] = MFMA16(af_[ii], bfr[jj], acc[4*(MH)+ii][jj]);                 \
    __builtin_amdgcn_s_setprio(0);                                                             \
    __builtin_amdgcn_sched_barrier(0);                                                         \
    if ((VMC) == 4) asm volatile("s_waitcnt vmcnt(4)" ::: "memory");                           \
    else if ((VMC) == 0) asm volatile("s_waitcnt vmcnt(0)" ::: "memory");                      \
    __builtin_amdgcn_s_barrier();                                                              \
    __builtin_amdgcn_sched_barrier(0);                                                         \
} while (0)

#define STAGE6(SRC, STREG, STBUF, STKK, STTILE) do {                                           \
    u16* dst_ = &lds[(STREG) + (2*(STBUF)+(STKK)) * 8192];                                     \
    _Pragma("unroll") for (int h2 = 0; h2 < 2; ++h2) {                                         \
        int c_ = tid + h2 * 512;                                                               \
        int u_ = c_ ^ ((c_ >> 3) & 3);                                                         \
        gl_lds16(&(SRC)[(size_t)(u_ >> 2) * 768 + (STTILE)*64 + (STKK)*32 + (u_ & 3)*8],       \
                 &dst_[c_ * 8]);                                                               \
    }                                                                                          \
} while (0)

__global__ __launch_bounds__(512, 2) void k_gemm_qkv(const u16* __restrict__ A,
                                                     const u16* __restrict__ BT,
                                                     const float* __restrict__ bias,
                                                     u16* __restrict__ Qb,
                                                     u16* __restrict__ Kb,
                                                     u16* __restrict__ Vtg) {
    extern __shared__ u16 lds[];
    const int tid = threadIdx.x;
    const int wave = tid >> 6, lane = tid & 63;
    const int wr = wave >> 2, wc = wave & 3;
    const int g = lane >> 4, lr = lane & 15;
    const int gsw = (g ^ ((lr >> 1) & 3)) * 8;

    // XCD-aware bijective remap (288 % 8 == 0): each XCD -> 4 contiguous M-stripes
    int orig = blockIdx.x;
    int wg = (orig & 7) * 36 + (orig >> 3);
    int bx = wg % 9, by = wg / 9;
    const int m0 = by * 256, n0 = bx * 256;

    const u16* Asrc = A + (size_t)m0 * 768;
    const u16* Bsrc = BT + (size_t)n0 * 768;

    f32x4 acc[8][4];
#pragma unroll
    for (int i = 0; i < 8; ++i)
#pragma unroll
        for (int j = 0; j < 4; ++j) acc[i][j] = (f32x4){0.f, 0.f, 0.f, 0.f};
    short8 bfr[4];

    // prologue: tile0 (all 4 halves) + tile1 K-half0
    STAGE6(Asrc, 0,     0, 0, 0);
    STAGE6(Bsrc, 32768, 0, 0, 0);
    STAGE6(Asrc, 0,     0, 1, 0);
    STAGE6(Bsrc, 32768, 0, 1, 0);
    STAGE6(Asrc, 0,     1, 0, 1);
    STAGE6(Bsrc, 32768, 1, 0, 1);
    asm volatile("s_waitcnt vmcnt(4)" ::: "memory");
    __builtin_amdgcn_s_barrier();
    __builtin_amdgcn_sched_barrier(0);

    // main loop: iters j=0..4, tiles (2j, 2j+1); stages per slot-liveness schedule
    for (int j = 0; j < 5; ++j) {
        const int t1 = 2*j + 1, t2 = 2*j + 2, t3 = 2*j + 3;
        PHASE(0,0,0, 1, 1, Asrc, 0,     1,1, t1, -1);
        PHASE(0,0,1, 0, 1, Bsrc, 32768, 1,1, t1, -1);
        PHASE(0,1,0, 1, 1, Asrc, 0,     0,0, t2, -1);
        PHASE(0,1,1, 0, 1, Bsrc, 32768, 0,0, t2,  4);
        PHASE(1,0,0, 1, 1, Asrc, 0,     0,1, t2, -1);
        PHASE(1,0,1, 0, 1, Bsrc, 32768, 0,1, t2, -1);
        PHASE(1,1,0, 1, 1, Asrc, 0,     1,0, t3, -1);
        PHASE(1,1,1, 0, 1, Bsrc, 32768, 1,0, t3,  4);
    }
    // peeled final iter: tiles (10, 11); only buf1-Kh1 <- tile 11 still needs staging
    PHASE(0,0,0, 1, 1, Asrc, 0,     1,1, 11, -1);
    PHASE(0,0,1, 0, 1, Bsrc, 32768, 1,1, 11, -1);
    PHASE(0,1,0, 1, 0, Asrc, 0,     0,0,  0, -1);
    PHASE(0,1,1, 0, 0, Asrc, 0,     0,0,  0,  0);
    PHASE(1,0,0, 1, 0, Asrc, 0,     0,0,  0, -1);
    PHASE(1,0,1, 0, 0, Asrc, 0,     0,0,  0, -1);
    PHASE(1,1,0, 1, 0, Asrc, 0,     0,0,  0, -1);
    PHASE(1,1,1, 0, 0, Asrc, 0,     0,0,  0, -1);

    // epilogue: scatter with bias; Q/K row-major per head, V transposed [bh][d][t]
#pragma unroll
    for (int i = 0; i < 8; ++i) {
        int row = m0 + 128 * wr + 16 * i + 4 * g;
#pragma unroll
        for (int jb = 0; jb < 4; ++jb) {
            int col = n0 + 64 * wc + 16 * jb + lr;
            int part = col / 768;
            int jj = col - part * 768;
            int h = jj / 96, d = jj - h * 96;
            float bsv = bias[col];
#pragma unroll
            for (int r = 0; r < 4; ++r) {
                int rw = row + r;
                int t = rw & 1023, bb = rw >> 10;
                int bh = bb * 8 + h;
                u16 val = f2bf(acc[i][jb][r] + bsv);
                if (part == 0)      Qb[((size_t)bh * 1024 + t) * 96 + d] = val;
                else if (part == 1) Kb[((size_t)bh * 1024 + t) * 96 + d] = val;
                else                Vtg[((size_t)bh * 96 + d) * 1024 + t] = val;
            }
        }
    }
}

// ---------------- flash attention ----------------
// grid (8, 64): paired q-tiles (z, 15-z) for load balance; XCD-swizzled bh

__global__ __launch_bounds__(256) void k_attn(const u16* __restrict__ Qb,
                                              const u16* __restrict__ Kb,
                                              const u16* __restrict__ Vtg,
                                              u16* __restrict__ Yatt) {
    __shared__ __align__(16) u16 KsL[2][64 * 96];  // linear [t][d] (gload_lds dest)
    __shared__ __align__(16) u16 VtL[2][96 * 72];  // [d][t] pad 72
    __shared__ __align__(16) u16 Ps[4][16 * 72];   // per-wave P [16][64] pad 72

    const int tid = threadIdx.x;
    const int wave = tid >> 6, lane = tid & 63;
    const int g = lane >> 4, lr = lane & 15;

    int id = blockIdx.y * 8 + blockIdx.x;
    int xcd = id & 7, slot = id >> 3;
    int nid = xcd * 64 + slot;
    int z = nid & 7, bh = nid >> 3;

    const size_t qkbase = (size_t)bh * 1024 * 96;
    const size_t vbase  = (size_t)bh * 96 * 1024;
    const float scale = 0.10206207261596577f; // 1/sqrt(96)
    const int b = bh >> 3, h = bh & 7;

    for (int seg = 0; seg < 2; ++seg) {
        const int qt = (seg == 0) ? z : 15 - z;
        const int q0 = qt * 64;

        short8 qf[3];
        {
            int qrow = q0 + 16 * wave + lr;
#pragma unroll
            for (int kk = 0; kk < 3; ++kk)
                qf[kk] = *(const short8*)&Qb[qkbase + (size_t)qrow * 96 + 32 * kk + 8 * g];
        }

        float m_r[4], l_r[4];
        f32x4 o[6];
#pragma unroll
        for (int r = 0; r < 4; ++r) { m_r[r] = -3e38f; l_r[r] = 0.f; }
#pragma unroll
        for (int c = 0; c < 6; ++c) o[c] = (f32x4){0.f, 0.f, 0.f, 0.f};

        u32x4 rv[3];
#pragma unroll
        for (int it = 0; it < 3; ++it) {
            int c = tid + it * 256;
            gl_lds16(&Kb[qkbase + (size_t)(c / 12) * 96 + (c % 12) * 8], &KsL[0][c * 8]);
        }
#pragma unroll
        for (int it = 0; it < 3; ++it) {
            int c = tid + it * 256;
            rv[it] = *(const u32x4*)&Vtg[vbase + (size_t)(c >> 3) * 1024 + ((c & 7) << 3)];
        }
#pragma unroll
        for (int it = 0; it < 3; ++it) {
            int c = tid + it * 256;
            *(u32x4*)&VtL[0][(c >> 3) * 72 + ((c & 7) << 3)] = rv[it];
        }
        __syncthreads();

        for (int kt = 0; kt <= qt; ++kt) {
            const int cur = kt & 1;
            const bool pf = kt < qt;
            if (pf) {
                const int nk = (kt + 1) * 64;
#pragma unroll
                for (int it = 0; it < 3; ++it) {
                    int c = tid + it * 256;
                    gl_lds16(&Kb[qkbase + (size_t)(nk + c / 12) * 96 + (c % 12) * 8],
                             &KsL[cur ^ 1][c * 8]);
                }
#pragma unroll
                for (int it = 0; it < 3; ++it) {
                    int c = tid + it * 256;
                    rv[it] = *(const u32x4*)&Vtg[vbase + (size_t)(c >> 3) * 1024 + nk + ((c & 7) << 3)];
                }
            }

            f32x4 s[4];
#pragma unroll
            for (int j = 0; j < 4; ++j) {
                s[j] = (f32x4){0.f, 0.f, 0.f, 0.f};
#pragma unroll
                for (int kk = 0; kk < 3; ++kk) {
                    short8 kf = *(const short8*)&KsL[cur][(16 * j + lr) * 96 + 32 * kk + 8 * g];
                    s[j] = MFMA16(qf[kk], kf, s[j]);
                }
            }
#pragma unroll
            for (int j = 0; j < 4; ++j)
#pragma unroll
                for (int r = 0; r < 4; ++r) s[j][r] *= scale;

            if (kt == qt) {
#pragma unroll
                for (int j = 0; j < 4; ++j) {
                    int lc = 16 * j + lr;
#pragma unroll
                    for (int r = 0; r < 4; ++r) {
                        int lrow = 16 * wave + 4 * g + r;
                        if (lc > lrow) s[j][r] = -3e38f;
                    }
                }
            }

            float alpha[4], rsum[4];
#pragma unroll
            for (int r = 0; r < 4; ++r) {
                float mx = fmaxf(fmaxf(s[0][r], s[1][r]), fmaxf(s[2][r], s[3][r]));
#pragma unroll
                for (int off = 1; off < 16; off <<= 1)
                    mx = fmaxf(mx, __shfl_xor(mx, off, 64));
                float mnew = fmaxf(m_r[r], mx);
                alpha[r] = __expf(m_r[r] - mnew);
                m_r[r] = mnew;
                rsum[r] = 0.f;
            }
#pragma unroll
            for (int j = 0; j < 4; ++j)
#pragma unroll
                for (int r = 0; r < 4; ++r) {
                    float p = __expf(s[j][r] - m_r[r]);
                    rsum[r] += p;
                    Ps[wave][(4 * g + r) * 72 + 16 * j + lr] = f2bf(p);
                }
#pragma unroll
            for (int r = 0; r < 4; ++r) {
#pragma unroll
                for (int off = 1; off < 16; off <<= 1)
                    rsum[r] += __shfl_xor(rsum[r], off, 64);
                l_r[r] = l_r[r] * alpha[r] + rsum[r];
            }
#pragma unroll
            for (int c = 0; c < 6; ++c)
#pragma unroll
                for (int r = 0; r < 4; ++r) o[c][r] *= alpha[r];

            short8 pfr[2];
#pragma unroll
            for (int kk = 0; kk < 2; ++kk)
                pfr[kk] = *(const short8*)&Ps[wave][lr * 72 + 32 * kk + 8 * g];
#pragma unroll
            for (int c = 0; c < 6; ++c) {
#pragma unroll
                for (int kk = 0; kk < 2; ++kk) {
                    short8 vf = *(const short8*)&VtL[cur][(16 * c + lr) * 72 + 32 * kk + 8 * g];
                    o[c] = MFMA16(pfr[kk], vf, o[c]);
                }
            }

            if (pf) {
#pragma unroll
                for (int it = 0; it < 3; ++it) {
                    int c = tid + it * 256;
                    *(u32x4*)&VtL[cur ^ 1][(c >> 3) * 72 + ((c & 7) << 3)] = rv[it];
                }
            }
            __syncthreads();
        }

#pragma unroll
        for (int r = 0; r < 4; ++r) {
            int t = q0 + 16 * wave + 4 * g + r;
            float inv = 1.0f / l_r[r];
            size_t rowoff = ((size_t)b * 1024 + t) * 768 + h * 96;
#pragma unroll
            for (int c = 0; c < 6; ++c)
                Yatt[rowoff + 16 * c + lr] = f2bf(o[c][r] * inv);
        }
        __syncthreads();
    }
}

// ---------------- GEMM2: out = yatt @ w_proj + b_proj (fp32 out) ----------------

__global__ __launch_bounds__(256) void k_gemm_out(const u16* __restrict__ A,
                                                  const u16* __restrict__ BT,
                                                  const float* __restrict__ bias,
                                                  float* __restrict__ out) {
    const int K = 768;
    __shared__ __align__(16) u16 As[128 * 32];
    __shared__ __align__(16) u16 Bs[128 * 32];
    const int tid = threadIdx.x;
    const int wave = tid >> 6, lane = tid & 63;
    const int wr = wave >> 1, wc = wave & 1;
    const int g = lane >> 4, lr = lane & 15;
    const int m0 = blockIdx.y * 128, n0 = blockIdx.x * 128;

    f32x4 acc[4][4];
#pragma unroll
    for (int i = 0; i < 4; ++i)
#pragma unroll
        for (int j = 0; j < 4; ++j) acc[i][j] = (f32x4){0.f, 0.f, 0.f, 0.f};

    for (int k0 = 0; k0 < K; k0 += 32) {
        __syncthreads();
#pragma unroll
        for (int it = 0; it < 2; ++it) {
            int c = tid + it * 256;
            int m = c >> 2, k8 = (c & 3) << 3;
            gl_lds16(&A[(size_t)(m0 + m) * K + k0 + k8], &As[c * 8]);
            gl_lds16(&BT[(size_t)(n0 + m) * K + k0 + k8], &Bs[c * 8]);
        }
        __syncthreads();
        short8 af[4], bf[4];
#pragma unroll
        for (int i = 0; i < 4; ++i)
            af[i] = *(const short8*)&As[(64 * wr + 16 * i + lr) * 32 + 8 * g];
#pragma unroll
        for (int j = 0; j < 4; ++j)
            bf[j] = *(const short8*)&Bs[(64 * wc + 16 * j + lr) * 32 + 8 * g];
#pragma unroll
        for (int i = 0; i < 4; ++i)
#pragma unroll
            for (int j = 0; j < 4; ++j)
                acc[i][j] = MFMA16(af[i], bf[j], acc[i][j]);
    }

#pragma unroll
    for (int i = 0; i < 4; ++i) {
        int row = m0 + 64 * wr + 16 * i + 4 * g;
#pragma unroll
        for (int j = 0; j < 4; ++j) {
            int col = n0 + 64 * wc + 16 * j + lr;
            float bsv = bias[col];
#pragma unroll
            for (int r = 0; r < 4; ++r)
                out[(size_t)(row + r) * 768 + col] = acc[i][j][r] + bsv;
        }
    }
}

// ---------------- launch ----------------

extern "C" void kernel_launch(void* const* d_in, const int* in_sizes, int n_in,
                              void* d_out, int out_size, void* d_ws, size_t ws_size,
                              hipStream_t stream) {
    const float* x      = (const float*)d_in[0];
    const float* w_qkv  = (const float*)d_in[1];
    const float* b_qkv  = (const float*)d_in[2];
    const float* w_proj = (const float*)d_in[3];
    const float* b_proj = (const float*)d_in[4];
    float* out = (float*)d_out;

    u16* xb    = (u16*)d_ws;            // 6291456
    u16* wqkvT = xb + 6291456;          // 1769472
    u16* wpT   = wqkvT + 1769472;       // 589824
    u16* Qb    = wpT + 589824;          // 6291456
    u16* Kb    = Qb + 6291456;          // 6291456
    u16* Vtg   = Kb + 6291456;          // 6291456 ([bh][d][t])
    u16* Yatt  = Vtg + 6291456;         // 6291456

    static bool attr_set = false;
    if (!attr_set) {
        hipFuncSetAttribute((const void*)k_gemm_qkv,
                            hipFuncAttributeMaxDynamicSharedMemorySize, 131072);
        attr_set = true;
    }

    k_cvt_x<<<6144, 256, 0, stream>>>(x, xb, 6291456);
    k_cvt_T<<<dim3(36, 12), 256, 0, stream>>>(w_qkv, wqkvT, 768, 2304);
    k_cvt_T<<<dim3(12, 12), 256, 0, stream>>>(w_proj, wpT, 768, 768);
    k_gemm_qkv<<<288, 512, 131072, stream>>>(xb, wqkvT, b_qkv, Qb, Kb, Vtg);
    k_attn<<<dim3(8, 64), 256, 0, stream>>>(Qb, Kb, Vtg, Yatt);
    k_gemm_out<<<dim3(6, 64), 256, 0, stream>>>(Yatt, wpT, b_proj, out);
}

// Round 4
// 137.491 us; speedup vs baseline: 1.1671x; 1.1671x over previous
//
#include <hip/hip_runtime.h>
#include <hip/hip_bf16.h>
#include <stdint.h>

typedef unsigned short u16;
typedef unsigned int u32;
typedef __attribute__((ext_vector_type(8))) short short8;
typedef __attribute__((ext_vector_type(4))) float f32x4;
typedef __attribute__((ext_vector_type(4))) unsigned int u32x4;
typedef __attribute__((ext_vector_type(4))) unsigned short u16x4;

#define MFMA16(a, b, c) __builtin_amdgcn_mfma_f32_16x16x32_bf16((a), (b), (c), 0, 0, 0)

__device__ __forceinline__ u16 f2bf(float f) {
    union { float f; uint32_t u; } v; v.f = f;
    return (u16)((v.u + 0x7FFFu + ((v.u >> 16) & 1u)) >> 16);
}

// async global -> LDS, 16 bytes per lane (dest must be linear: base + lane*16)
__device__ __forceinline__ void gl_lds16(const u16* g, u16* l) {
    __builtin_amdgcn_global_load_lds(
        (const __attribute__((address_space(1))) u32*)g,
        (__attribute__((address_space(3))) u32*)l,
        16, 0, 0);
}

// ---------------- convert kernels ----------------

__global__ __launch_bounds__(256) void k_cvt_x(const float* __restrict__ in,
                                               u16* __restrict__ out, int n) {
    int i = (blockIdx.x * 256 + threadIdx.x) * 4;
    if (i >= n) return;
    f32x4 v = *(const f32x4*)(in + i);
    u16x4 o;
    o[0] = f2bf(v[0]); o[1] = f2bf(v[1]); o[2] = f2bf(v[2]); o[3] = f2bf(v[3]);
    *(u16x4*)(out + i) = o;
}

// LDS-tiled transpose+convert: out[n*K+k] = bf16(in[k*N+n]); K,N multiples of 64
__global__ __launch_bounds__(256) void k_cvt_T(const float* __restrict__ in,
                                               u16* __restrict__ out, int K, int N) {
    __shared__ u16 t[64][72];
    const int kb = blockIdx.y * 64, nb = blockIdx.x * 64;
    const int tid = threadIdx.x;
    const int r = tid >> 4, c4 = (tid & 15) << 2;
#pragma unroll
    for (int p = 0; p < 4; ++p) {
        int k = r + p * 16;
        f32x4 v = *(const f32x4*)&in[(size_t)(kb + k) * N + nb + c4];
#pragma unroll
        for (int q = 0; q < 4; ++q) t[c4 + q][k] = f2bf(v[q]);
    }
    __syncthreads();
#pragma unroll
    for (int p = 0; p < 4; ++p) {
        int nn = r + p * 16;
        u16x4 o;
#pragma unroll
        for (int q = 0; q < 4; ++q) o[q] = t[nn][c4 + q];
        *(u16x4*)&out[(size_t)(nb + nn) * K + kb + c4] = o;
    }
}

// ---------------- shared GEMM core: 128x128 tile, BK=64, swizzled LDS ----------------
// LDS[r][slot] holds global chunk u = slot ^ (r&7)  (16B chunks, 8 per 128B row)
// read for (kk,g): slot = (4*kk+g) ^ (lr&7)  -> 2-way max bank aliasing (free)

__device__ __forceinline__ void gemm_core_128(const u16* __restrict__ Asrc, int lda,
                                              const u16* __restrict__ Bsrc,
                                              u16* As, u16* Bs, int tid,
                                              f32x4 acc[4][4]) {
    const int lane = tid & 63, wave = tid >> 6;
    const int wr = wave >> 1, wc = wave & 1;
    const int g = lane >> 4, lr = lane & 15;
    for (int k0 = 0; k0 < 768; k0 += 64) {
        __syncthreads();
#pragma unroll
        for (int it = 0; it < 4; ++it) {
            int c = tid + it * 256;
            int r = c >> 3, s = c & 7, u = s ^ (r & 7);
            gl_lds16(&Asrc[(size_t)r * lda + k0 + u * 8], &As[c * 8]);
            gl_lds16(&Bsrc[(size_t)r * 768 + k0 + u * 8], &Bs[c * 8]);
        }
        __syncthreads();
#pragma unroll
        for (int kk = 0; kk < 2; ++kk) {
            const int slot = ((4 * kk + g) ^ (lr & 7)) << 3;
            short8 af[4], bfv[4];
#pragma unroll
            for (int i = 0; i < 4; ++i)
                af[i] = *(const short8*)&As[(64 * wr + 16 * i + lr) * 64 + slot];
#pragma unroll
            for (int j = 0; j < 4; ++j)
                bfv[j] = *(const short8*)&Bs[(64 * wc + 16 * j + lr) * 64 + slot];
#pragma unroll
            for (int i = 0; i < 4; ++i)
#pragma unroll
                for (int j = 0; j < 4; ++j)
                    acc[i][j] = MFMA16(af[i], bfv[j], acc[i][j]);
        }
    }
}

// ---------------- GEMM1: qkv = x @ w_qkv + b (row-major [8192][2304] bf16) ----------------

__global__ __launch_bounds__(256) void k_gemm_qkv(const u16* __restrict__ A,
                                                  const u16* __restrict__ BT,
                                                  const float* __restrict__ bias,
                                                  u16* __restrict__ qkv) {
    __shared__ __align__(16) u16 As[128 * 64];
    __shared__ __align__(16) u16 Bs[128 * 64];
    const int tid = threadIdx.x;
    int id = blockIdx.x;                        // 1152 blocks
    int nid = (id & 7) * 144 + (id >> 3);       // XCD-chunked remap (1152 % 8 == 0)
    int by = nid / 18, bx = nid - by * 18;
    const int m0 = by * 128, n0 = bx * 128;

    f32x4 acc[4][4];
#pragma unroll
    for (int i = 0; i < 4; ++i)
#pragma unroll
        for (int j = 0; j < 4; ++j) acc[i][j] = (f32x4){0.f, 0.f, 0.f, 0.f};

    gemm_core_128(A + (size_t)m0 * 768, 768, BT + (size_t)n0 * 768, As, Bs, tid, acc);

    const int lane = tid & 63, wave = tid >> 6;
    const int wr = wave >> 1, wc = wave & 1;
    const int g = lane >> 4, lr = lane & 15;
#pragma unroll
    for (int i = 0; i < 4; ++i) {
        int row = m0 + 64 * wr + 16 * i + 4 * g;
#pragma unroll
        for (int j = 0; j < 4; ++j) {
            int col = n0 + 64 * wc + 16 * j + lr;
            float bsv = bias[col];
#pragma unroll
            for (int r = 0; r < 4; ++r)
                qkv[(size_t)(row + r) * 2304 + col] = f2bf(acc[i][j][r] + bsv);
        }
    }
}

// ---------------- k_vT: Vtg[bh][d][t] = qkv[b*1024+t][1536 + h*96 + d] ----------------

__global__ __launch_bounds__(256) void k_vT(const u16* __restrict__ qkv,
                                            u16* __restrict__ Vtg) {
    __shared__ __align__(16) u16 Vt[96 * 72];   // [d][t] pad 72
    const int tb = blockIdx.x, bh = blockIdx.y;
    const int b = bh >> 3, h = bh & 7;
    const int tid = threadIdx.x;
    const int vcol = 1536 + h * 96;
#pragma unroll
    for (int it = 0; it < 3; ++it) {
        int c = tid + it * 256;
        int r = c / 12, s = c - r * 12;
        u32x4 v = *(const u32x4*)&qkv[(size_t)(b * 1024 + tb * 64 + r) * 2304 + vcol + s * 8];
        const u16* vs = (const u16*)&v;
#pragma unroll
        for (int p = 0; p < 8; ++p)
            Vt[(s * 8 + p) * 72 + r] = vs[p];
    }
    __syncthreads();
#pragma unroll
    for (int it = 0; it < 3; ++it) {
        int c = tid + it * 256;
        int d = c >> 3, t8 = (c & 7) << 3;
        u32x4 o = *(const u32x4*)&Vt[d * 72 + t8];
        *(u32x4*)&Vtg[((size_t)bh * 96 + d) * 1024 + tb * 64 + t8] = o;
    }
}

// ---------------- flash attention ----------------
// grid (8, 64): paired q-tiles (z, 15-z); XCD-swizzled bh; Y written into qkv Q region

__global__ __launch_bounds__(256) void k_attn(u16* __restrict__ qkv,
                                              const u16* __restrict__ Vtg) {
    extern __shared__ u16 sm[];
    u16* KsB = sm;                   // [2][64*128] swizzled K tiles
    u16* VtB = sm + 16384;           // [2][96*72]  V^T tiles
    u16* PsB = sm + 16384 + 13824;   // [4][16*72]  per-wave P

    const int tid = threadIdx.x;
    const int wave = tid >> 6, lane = tid & 63;
    const int g = lane >> 4, lr = lane & 15;
    u16* Ps = PsB + wave * (16 * 72);

    int id = blockIdx.y * 8 + blockIdx.x;
    int xcd = id & 7, slot = id >> 3;
    int nid = xcd * 64 + slot;
    int z = nid & 7, bh = nid >> 3;
    const int b = bh >> 3, h = bh & 7;

    const size_t rowb = (size_t)b * 1024;
    const int qcol = h * 96;
    const int kcol = 768 + h * 96;
    const size_t vbase = (size_t)bh * 96 * 1024;
    const float scale = 0.10206207261596577f; // 1/sqrt(96)

    for (int seg = 0; seg < 2; ++seg) {
        const int qt = (seg == 0) ? z : 15 - z;
        const int q0 = qt * 64;

        short8 qf[3];
        {
            int qrow = q0 + 16 * wave + lr;
#pragma unroll
            for (int kk = 0; kk < 3; ++kk)
                qf[kk] = *(const short8*)&qkv[(rowb + qrow) * 2304 + qcol + 32 * kk + 8 * g];
        }

        float m_r[4], l_r[4];
        f32x4 o[6];
#pragma unroll
        for (int r = 0; r < 4; ++r) { m_r[r] = -3e38f; l_r[r] = 0.f; }
#pragma unroll
        for (int c = 0; c < 6; ++c) o[c] = (f32x4){0.f, 0.f, 0.f, 0.f};

        u32x4 rk[3], rv[3];
        // prologue: load tile 0, write to buf 0
#pragma unroll
        for (int it = 0; it < 3; ++it) {
            int c = tid + it * 256;
            int r = c / 12, s = c - r * 12;
            rk[it] = *(const u32x4*)&qkv[(rowb + r) * 2304 + kcol + s * 8];
            rv[it] = *(const u32x4*)&Vtg[vbase + (size_t)(c >> 3) * 1024 + ((c & 7) << 3)];
        }
#pragma unroll
        for (int it = 0; it < 3; ++it) {
            int c = tid + it * 256;
            int r = c / 12, s = c - r * 12;
            *(u32x4*)&KsB[r * 128 + ((s ^ (r & 7)) << 3)] = rk[it];
            *(u32x4*)&VtB[(c >> 3) * 72 + ((c & 7) << 3)] = rv[it];
        }
        __syncthreads();

        for (int kt = 0; kt <= qt; ++kt) {
            const int cur = kt & 1;
            const bool pf = kt < qt;
            if (pf) { // issue-early next-tile loads
                const int nk = (kt + 1) * 64;
#pragma unroll
                for (int it = 0; it < 3; ++it) {
                    int c = tid + it * 256;
                    int r = c / 12, s = c - r * 12;
                    rk[it] = *(const u32x4*)&qkv[(rowb + nk + r) * 2304 + kcol + s * 8];
                    rv[it] = *(const u32x4*)&Vtg[vbase + (size_t)(c >> 3) * 1024 + nk + ((c & 7) << 3)];
                }
            }
            const u16* Ks = KsB + cur * 8192;
            const u16* Vt = VtB + cur * 6912;

            // S = Q @ K^T
            f32x4 s4[4];
#pragma unroll
            for (int j = 0; j < 4; ++j) {
                s4[j] = (f32x4){0.f, 0.f, 0.f, 0.f};
#pragma unroll
                for (int kk = 0; kk < 3; ++kk) {
                    short8 kf = *(const short8*)&Ks[(16 * j + lr) * 128 +
                                                    (((4 * kk + g) ^ (lr & 7)) << 3)];
                    s4[j] = MFMA16(qf[kk], kf, s4[j]);
                }
            }
#pragma unroll
            for (int j = 0; j < 4; ++j)
#pragma unroll
                for (int r = 0; r < 4; ++r) s4[j][r] *= scale;

            if (kt == qt) { // diagonal mask
#pragma unroll
                for (int j = 0; j < 4; ++j) {
                    int lc = 16 * j + lr;
#pragma unroll
                    for (int r = 0; r < 4; ++r) {
                        int lrow = 16 * wave + 4 * g + r;
                        if (lc > lrow) s4[j][r] = -3e38f;
                    }
                }
            }

            // online softmax
            float alpha[4], rsum[4];
#pragma unroll
            for (int r = 0; r < 4; ++r) {
                float mx = fmaxf(fmaxf(s4[0][r], s4[1][r]), fmaxf(s4[2][r], s4[3][r]));
#pragma unroll
                for (int off = 1; off < 16; off <<= 1)
                    mx = fmaxf(mx, __shfl_xor(mx, off, 64));
                float mnew = fmaxf(m_r[r], mx);
                alpha[r] = __expf(m_r[r] - mnew);
                m_r[r] = mnew;
                rsum[r] = 0.f;
            }
#pragma unroll
            for (int j = 0; j < 4; ++j)
#pragma unroll
                for (int r = 0; r < 4; ++r) {
                    float p = __expf(s4[j][r] - m_r[r]);
                    rsum[r] += p;
                    Ps[(4 * g + r) * 72 + 16 * j + lr] = f2bf(p);
                }
#pragma unroll
            for (int r = 0; r < 4; ++r) {
#pragma unroll
                for (int off = 1; off < 16; off <<= 1)
                    rsum[r] += __shfl_xor(rsum[r], off, 64);
                l_r[r] = l_r[r] * alpha[r] + rsum[r];
            }
#pragma unroll
            for (int c = 0; c < 6; ++c)
#pragma unroll
                for (int r = 0; r < 4; ++r) o[c][r] *= alpha[r];

            // PV
            short8 pfr[2];
#pragma unroll
            for (int kk = 0; kk < 2; ++kk)
                pfr[kk] = *(const short8*)&Ps[lr * 72 + 32 * kk + 8 * g];
#pragma unroll
            for (int c = 0; c < 6; ++c) {
#pragma unroll
                for (int kk = 0; kk < 2; ++kk) {
                    short8 vf = *(const short8*)&Vt[(16 * c + lr) * 72 + 32 * kk + 8 * g];
                    o[c] = MFMA16(pfr[kk], vf, o[c]);
                }
            }

            if (pf) { // write-late into the other buffer
#pragma unroll
                for (int it = 0; it < 3; ++it) {
                    int c = tid + it * 256;
                    int r = c / 12, s = c - r * 12;
                    *(u32x4*)&KsB[(cur ^ 1) * 8192 + r * 128 + ((s ^ (r & 7)) << 3)] = rk[it];
                    *(u32x4*)&VtB[(cur ^ 1) * 6912 + (c >> 3) * 72 + ((c & 7) << 3)] = rv[it];
                }
            }
            __syncthreads();
        }

        // epilogue: write Y into qkv Q region (safe: this block's Q rows already in regs;
        // other blocks of same bh own disjoint q-tiles; K/V regions untouched)
#pragma unroll
        for (int r = 0; r < 4; ++r) {
            int t = q0 + 16 * wave + 4 * g + r;
            float inv = 1.0f / l_r[r];
            size_t rowoff = (rowb + t) * 2304 + qcol;
#pragma unroll
            for (int c = 0; c < 6; ++c)
                qkv[rowoff + 16 * c + lr] = f2bf(o[c][r] * inv);
        }
        __syncthreads();
    }
}

// ---------------- GEMM2: out = Y @ w_proj + b_proj (fp32 out), A = qkv cols 0..767 ----------------

__global__ __launch_bounds__(256) void k_gemm_out(const u16* __restrict__ A,   // qkv, stride 2304
                                                  const u16* __restrict__ BT,  // [768][768]
                                                  const float* __restrict__ bias,
                                                  float* __restrict__ out) {
    __shared__ __align__(16) u16 As[128 * 64];
    __shared__ __align__(16) u16 Bs[128 * 64];
    const int tid = threadIdx.x;
    int id = blockIdx.x;                        // 384 blocks
    int nid = (id & 7) * 48 + (id >> 3);        // XCD-chunked remap (384 % 8 == 0)
    int by = nid / 6, bx = nid - by * 6;
    const int m0 = by * 128, n0 = bx * 128;

    f32x4 acc[4][4];
#pragma unroll
    for (int i = 0; i < 4; ++i)
#pragma unroll
        for (int j = 0; j < 4; ++j) acc[i][j] = (f32x4){0.f, 0.f, 0.f, 0.f};

    gemm_core_128(A + (size_t)m0 * 2304, 2304, BT + (size_t)n0 * 768, As, Bs, tid, acc);

    const int lane = tid & 63, wave = tid >> 6;
    const int wr = wave >> 1, wc = wave & 1;
    const int g = lane >> 4, lr = lane & 15;
#pragma unroll
    for (int i = 0; i < 4; ++i) {
        int row = m0 + 64 * wr + 16 * i + 4 * g;
#pragma unroll
        for (int j = 0; j < 4; ++j) {
            int col = n0 + 64 * wc + 16 * j + lr;
            float bsv = bias[col];
#pragma unroll
            for (int r = 0; r < 4; ++r)
                out[(size_t)(row + r) * 768 + col] = acc[i][j][r] + bsv;
        }
    }
}

// ---------------- launch ----------------

extern "C" void kernel_launch(void* const* d_in, const int* in_sizes, int n_in,
                              void* d_out, int out_size, void* d_ws, size_t ws_size,
                              hipStream_t stream) {
    const float* x      = (const float*)d_in[0];
    const float* w_qkv  = (const float*)d_in[1];
    const float* b_qkv  = (const float*)d_in[2];
    const float* w_proj = (const float*)d_in[3];
    const float* b_proj = (const float*)d_in[4];
    float* out = (float*)d_out;

    u16* xb    = (u16*)d_ws;            // 6291456
    u16* wqkvT = xb + 6291456;          // 1769472
    u16* wpT   = wqkvT + 1769472;       // 589824
    u16* qkv   = wpT + 589824;          // 18874368  [8192][2304]
    u16* Vtg   = qkv + 18874368;        // 6291456   [bh][96][1024]

    hipFuncSetAttribute((const void*)k_attn,
                        hipFuncAttributeMaxDynamicSharedMemorySize, 69632);

    k_cvt_x<<<6144, 256, 0, stream>>>(x, xb, 6291456);
    k_cvt_T<<<dim3(36, 12), 256, 0, stream>>>(w_qkv, wqkvT, 768, 2304);
    k_cvt_T<<<dim3(12, 12), 256, 0, stream>>>(w_proj, wpT, 768, 768);
    k_gemm_qkv<<<1152, 256, 0, stream>>>(xb, wqkvT, b_qkv, qkv);
    k_vT<<<dim3(16, 64), 256, 0, stream>>>(qkv, Vtg);
    k_attn<<<dim3(8, 64), 256, 69632, stream>>>(qkv, Vtg);
    k_gemm_out<<<384, 256, 0, stream>>>(qkv, wpT, b_proj, out);
}

// Round 5
// 126.324 us; speedup vs baseline: 1.2703x; 1.0884x over previous
//
#include <hip/hip_runtime.h>
#include <hip/hip_bf16.h>
#include <stdint.h>

typedef unsigned short u16;
typedef unsigned int u32;
typedef __attribute__((ext_vector_type(8))) short short8;
typedef __attribute__((ext_vector_type(4))) float f32x4;
typedef __attribute__((ext_vector_type(4))) unsigned int u32x4;
typedef __attribute__((ext_vector_type(4))) unsigned short u16x4;

#define MFMA16(a, b, c) __builtin_amdgcn_mfma_f32_16x16x32_bf16((a), (b), (c), 0, 0, 0)

__device__ __forceinline__ u16 f2bf(float f) {
    union { float f; uint32_t u; } v; v.f = f;
    return (u16)((v.u + 0x7FFFu + ((v.u >> 16) & 1u)) >> 16);
}

// async global -> LDS, 16 bytes per lane (dest must be linear: base + lane*16)
__device__ __forceinline__ void gl_lds16(const u16* g, u16* l) {
    __builtin_amdgcn_global_load_lds(
        (const __attribute__((address_space(1))) u32*)g,
        (__attribute__((address_space(3))) u32*)l,
        16, 0, 0);
}

// ---------------- convert kernels ----------------

__global__ __launch_bounds__(256) void k_cvt_x(const float* __restrict__ in,
                                               u16* __restrict__ out, int n) {
    int i = (blockIdx.x * 256 + threadIdx.x) * 4;
    if (i >= n) return;
    f32x4 v = *(const f32x4*)(in + i);
    u16x4 o;
    o[0] = f2bf(v[0]); o[1] = f2bf(v[1]); o[2] = f2bf(v[2]); o[3] = f2bf(v[3]);
    *(u16x4*)(out + i) = o;
}

// LDS-tiled transpose+convert: out[n*K+k] = bf16(in[k*N+n]); K,N multiples of 64
__global__ __launch_bounds__(256) void k_cvt_T(const float* __restrict__ in,
                                               u16* __restrict__ out, int K, int N) {
    __shared__ u16 t[64][72];
    const int kb = blockIdx.y * 64, nb = blockIdx.x * 64;
    const int tid = threadIdx.x;
    const int r = tid >> 4, c4 = (tid & 15) << 2;
#pragma unroll
    for (int p = 0; p < 4; ++p) {
        int k = r + p * 16;
        f32x4 v = *(const f32x4*)&in[(size_t)(kb + k) * N + nb + c4];
#pragma unroll
        for (int q = 0; q < 4; ++q) t[c4 + q][k] = f2bf(v[q]);
    }
    __syncthreads();
#pragma unroll
    for (int p = 0; p < 4; ++p) {
        int nn = r + p * 16;
        u16x4 o;
#pragma unroll
        for (int q = 0; q < 4; ++q) o[q] = t[nn][c4 + q];
        *(u16x4*)&out[(size_t)(nb + nn) * K + kb + c4] = o;
    }
}

// ---------------- shared GEMM core: 128x128 tile, BK=64, dbuf 2-phase pipeline ----------------
// LDS[r][slot] holds global chunk u = slot ^ (r&7)  (16B chunks, 8 per 128B row)
// read for (kk,g): slot = (4*kk+g) ^ (lr&7)  -> 2-way max bank aliasing (free)
// 2-phase: stage tile t+1 into buf^1, compute tile t from buf, ONE barrier/iter
// (WAR-safe: buf^1's readers finished before the previous barrier)

__device__ __forceinline__ void gemm_core_128_db(const u16* __restrict__ Asrc, int lda,
                                                 const u16* __restrict__ Bsrc,
                                                 u16* __restrict__ lds, int tid,
                                                 f32x4 acc[4][4]) {
    const int lane = tid & 63, wave = tid >> 6;
    const int wr = wave >> 1, wc = wave & 1;
    const int g = lane >> 4, lr = lane & 15;

    // prologue: stage tile 0 into buf0
#pragma unroll
    for (int it = 0; it < 4; ++it) {
        int c = tid + it * 256;
        int r = c >> 3, s = c & 7, u = s ^ (r & 7);
        gl_lds16(&Asrc[(size_t)r * lda + u * 8], &lds[c * 8]);
        gl_lds16(&Bsrc[(size_t)r * 768 + u * 8], &lds[8192 + c * 8]);
    }
    __syncthreads();

    for (int t = 0; t < 12; ++t) {
        const int cur = t & 1;
        if (t < 11) { // issue next-tile stage early (latency hides under compute)
            const int k0 = (t + 1) * 64;
            u16* dA = &lds[(cur ^ 1) * 16384];
            u16* dB = &lds[(cur ^ 1) * 16384 + 8192];
#pragma unroll
            for (int it = 0; it < 4; ++it) {
                int c = tid + it * 256;
                int r = c >> 3, s = c & 7, u = s ^ (r & 7);
                gl_lds16(&Asrc[(size_t)r * lda + k0 + u * 8], &dA[c * 8]);
                gl_lds16(&Bsrc[(size_t)r * 768 + k0 + u * 8], &dB[c * 8]);
            }
        }
        const u16* As = &lds[cur * 16384];
        const u16* Bs = &lds[cur * 16384 + 8192];
#pragma unroll
        for (int kk = 0; kk < 2; ++kk) {
            const int slot = ((4 * kk + g) ^ (lr & 7)) << 3;
            short8 af[4], bfv[4];
#pragma unroll
            for (int i = 0; i < 4; ++i)
                af[i] = *(const short8*)&As[(64 * wr + 16 * i + lr) * 64 + slot];
#pragma unroll
            for (int j = 0; j < 4; ++j)
                bfv[j] = *(const short8*)&Bs[(64 * wc + 16 * j + lr) * 64 + slot];
#pragma unroll
            for (int i = 0; i < 4; ++i)
#pragma unroll
                for (int j = 0; j < 4; ++j)
                    acc[i][j] = MFMA16(af[i], bfv[j], acc[i][j]);
        }
        if (t < 11) __syncthreads(); // vmcnt(0)+lgkmcnt(0)+barrier: next buf ready
    }
}

// ---------------- GEMM1: qkv = x @ w_qkv + b (row-major [8192][2304] bf16) ----------------

__global__ __launch_bounds__(256) void k_gemm_qkv(const u16* __restrict__ A,
                                                  const u16* __restrict__ BT,
                                                  const float* __restrict__ bias,
                                                  u16* __restrict__ qkv) {
    __shared__ __align__(16) u16 lds[2 * 16384];
    const int tid = threadIdx.x;
    int id = blockIdx.x;                        // 1152 blocks
    int nid = (id & 7) * 144 + (id >> 3);       // XCD-chunked remap (1152 % 8 == 0)
    int by = nid / 18, bx = nid - by * 18;
    const int m0 = by * 128, n0 = bx * 128;

    f32x4 acc[4][4];
#pragma unroll
    for (int i = 0; i < 4; ++i)
#pragma unroll
        for (int j = 0; j < 4; ++j) acc[i][j] = (f32x4){0.f, 0.f, 0.f, 0.f};

    gemm_core_128_db(A + (size_t)m0 * 768, 768, BT + (size_t)n0 * 768, lds, tid, acc);

    const int lane = tid & 63, wave = tid >> 6;
    const int wr = wave >> 1, wc = wave & 1;
    const int g = lane >> 4, lr = lane & 15;
#pragma unroll
    for (int i = 0; i < 4; ++i) {
        int row = m0 + 64 * wr + 16 * i + 4 * g;
#pragma unroll
        for (int j = 0; j < 4; ++j) {
            int col = n0 + 64 * wc + 16 * j + lr;
            float bsv = bias[col];
#pragma unroll
            for (int r = 0; r < 4; ++r)
                qkv[(size_t)(row + r) * 2304 + col] = f2bf(acc[i][j][r] + bsv);
        }
    }
}

// ---------------- k_vT: Vtg[bh][d][t] = qkv[b*1024+t][1536 + h*96 + d] ----------------

__global__ __launch_bounds__(256) void k_vT(const u16* __restrict__ qkv,
                                            u16* __restrict__ Vtg) {
    __shared__ __align__(16) u16 Vt[96 * 72];   // [d][t] pad 72
    const int tb = blockIdx.x, bh = blockIdx.y;
    const int b = bh >> 3, h = bh & 7;
    const int tid = threadIdx.x;
    const int vcol = 1536 + h * 96;
#pragma unroll
    for (int it = 0; it < 3; ++it) {
        int c = tid + it * 256;
        int r = c / 12, s = c - r * 12;
        u32x4 v = *(const u32x4*)&qkv[(size_t)(b * 1024 + tb * 64 + r) * 2304 + vcol + s * 8];
        const u16* vs = (const u16*)&v;
#pragma unroll
        for (int p = 0; p < 8; ++p)
            Vt[(s * 8 + p) * 72 + r] = vs[p];
    }
    __syncthreads();
#pragma unroll
    for (int it = 0; it < 3; ++it) {
        int c = tid + it * 256;
        int d = c >> 3, t8 = (c & 7) << 3;
        u32x4 o = *(const u32x4*)&Vt[d * 72 + t8];
        *(u32x4*)&Vtg[((size_t)bh * 96 + d) * 1024 + tb * 64 + t8] = o;
    }
}

// ---------------- flash attention ----------------
// grid (8, 64): paired q-tiles (z, 15-z); XCD-swizzled bh; Y written into qkv Q region

__global__ __launch_bounds__(256) void k_attn(u16* __restrict__ qkv,
                                              const u16* __restrict__ Vtg) {
    extern __shared__ u16 sm[];
    u16* KsB = sm;                   // [2][64*128] swizzled K tiles
    u16* VtB = sm + 16384;           // [2][96*72]  V^T tiles
    u16* PsB = sm + 16384 + 13824;   // [4][16*72]  per-wave P

    const int tid = threadIdx.x;
    const int wave = tid >> 6, lane = tid & 63;
    const int g = lane >> 4, lr = lane & 15;
    u16* Ps = PsB + wave * (16 * 72);

    int id = blockIdx.y * 8 + blockIdx.x;
    int xcd = id & 7, slot = id >> 3;
    int nid = xcd * 64 + slot;
    int z = nid & 7, bh = nid >> 3;
    const int b = bh >> 3, h = bh & 7;

    const size_t rowb = (size_t)b * 1024;
    const int qcol = h * 96;
    const int kcol = 768 + h * 96;
    const size_t vbase = (size_t)bh * 96 * 1024;
    const float scale = 0.10206207261596577f; // 1/sqrt(96)

    for (int seg = 0; seg < 2; ++seg) {
        const int qt = (seg == 0) ? z : 15 - z;
        const int q0 = qt * 64;

        short8 qf[3];
        {
            int qrow = q0 + 16 * wave + lr;
#pragma unroll
            for (int kk = 0; kk < 3; ++kk)
                qf[kk] = *(const short8*)&qkv[(rowb + qrow) * 2304 + qcol + 32 * kk + 8 * g];
        }

        float m_r[4], l_r[4];
        f32x4 o[6];
#pragma unroll
        for (int r = 0; r < 4; ++r) { m_r[r] = -3e38f; l_r[r] = 0.f; }
#pragma unroll
        for (int c = 0; c < 6; ++c) o[c] = (f32x4){0.f, 0.f, 0.f, 0.f};

        u32x4 rk[3], rv[3];
        // prologue: load tile 0, write to buf 0
#pragma unroll
        for (int it = 0; it < 3; ++it) {
            int c = tid + it * 256;
            int r = c / 12, s = c - r * 12;
            rk[it] = *(const u32x4*)&qkv[(rowb + r) * 2304 + kcol + s * 8];
            rv[it] = *(const u32x4*)&Vtg[vbase + (size_t)(c >> 3) * 1024 + ((c & 7) << 3)];
        }
#pragma unroll
        for (int it = 0; it < 3; ++it) {
            int c = tid + it * 256;
            int r = c / 12, s = c - r * 12;
            *(u32x4*)&KsB[r * 128 + ((s ^ (r & 7)) << 3)] = rk[it];
            *(u32x4*)&VtB[(c >> 3) * 72 + ((c & 7) << 3)] = rv[it];
        }
        __syncthreads();

        for (int kt = 0; kt <= qt; ++kt) {
            const int cur = kt & 1;
            const bool pf = kt < qt;
            if (pf) { // issue-early next-tile loads
                const int nk = (kt + 1) * 64;
#pragma unroll
                for (int it = 0; it < 3; ++it) {
                    int c = tid + it * 256;
                    int r = c / 12, s = c - r * 12;
                    rk[it] = *(const u32x4*)&qkv[(rowb + nk + r) * 2304 + kcol + s * 8];
                    rv[it] = *(const u32x4*)&Vtg[vbase + (size_t)(c >> 3) * 1024 + nk + ((c & 7) << 3)];
                }
            }
            const u16* Ks = KsB + cur * 8192;
            const u16* Vt = VtB + cur * 6912;

            // S = Q @ K^T
            f32x4 s4[4];
            __builtin_amdgcn_s_setprio(1);
#pragma unroll
            for (int j = 0; j < 4; ++j) {
                s4[j] = (f32x4){0.f, 0.f, 0.f, 0.f};
#pragma unroll
                for (int kk = 0; kk < 3; ++kk) {
                    short8 kf = *(const short8*)&Ks[(16 * j + lr) * 128 +
                                                    (((4 * kk + g) ^ (lr & 7)) << 3)];
                    s4[j] = MFMA16(qf[kk], kf, s4[j]);
                }
            }
            __builtin_amdgcn_s_setprio(0);
#pragma unroll
            for (int j = 0; j < 4; ++j)
#pragma unroll
                for (int r = 0; r < 4; ++r) s4[j][r] *= scale;

            if (kt == qt) { // diagonal mask
#pragma unroll
                for (int j = 0; j < 4; ++j) {
                    int lc = 16 * j + lr;
#pragma unroll
                    for (int r = 0; r < 4; ++r) {
                        int lrow = 16 * wave + 4 * g + r;
                        if (lc > lrow) s4[j][r] = -3e38f;
                    }
                }
            }

            // online softmax
            float alpha[4], rsum[4];
#pragma unroll
            for (int r = 0; r < 4; ++r) {
                float mx = fmaxf(fmaxf(s4[0][r], s4[1][r]), fmaxf(s4[2][r], s4[3][r]));
#pragma unroll
                for (int off = 1; off < 16; off <<= 1)
                    mx = fmaxf(mx, __shfl_xor(mx, off, 64));
                float mnew = fmaxf(m_r[r], mx);
                alpha[r] = __expf(m_r[r] - mnew);
                m_r[r] = mnew;
                rsum[r] = 0.f;
            }
#pragma unroll
            for (int j = 0; j < 4; ++j)
#pragma unroll
                for (int r = 0; r < 4; ++r) {
                    float p = __expf(s4[j][r] - m_r[r]);
                    rsum[r] += p;
                    Ps[(4 * g + r) * 72 + 16 * j + lr] = f2bf(p);
                }
#pragma unroll
            for (int r = 0; r < 4; ++r) {
#pragma unroll
                for (int off = 1; off < 16; off <<= 1)
                    rsum[r] += __shfl_xor(rsum[r], off, 64);
                l_r[r] = l_r[r] * alpha[r] + rsum[r];
            }
#pragma unroll
            for (int c = 0; c < 6; ++c)
#pragma unroll
                for (int r = 0; r < 4; ++r) o[c][r] *= alpha[r];

            // PV
            short8 pfr[2];
#pragma unroll
            for (int kk = 0; kk < 2; ++kk)
                pfr[kk] = *(const short8*)&Ps[lr * 72 + 32 * kk + 8 * g];
            __builtin_amdgcn_s_setprio(1);
#pragma unroll
            for (int c = 0; c < 6; ++c) {
#pragma unroll
                for (int kk = 0; kk < 2; ++kk) {
                    short8 vf = *(const short8*)&Vt[(16 * c + lr) * 72 + 32 * kk + 8 * g];
                    o[c] = MFMA16(pfr[kk], vf, o[c]);
                }
            }
            __builtin_amdgcn_s_setprio(0);

            if (pf) { // write-late into the other buffer
#pragma unroll
                for (int it = 0; it < 3; ++it) {
                    int c = tid + it * 256;
                    int r = c / 12, s = c - r * 12;
                    *(u32x4*)&KsB[(cur ^ 1) * 8192 + r * 128 + ((s ^ (r & 7)) << 3)] = rk[it];
                    *(u32x4*)&VtB[(cur ^ 1) * 6912 + (c >> 3) * 72 + ((c & 7) << 3)] = rv[it];
                }
            }
            __syncthreads();
        }

        // epilogue: write Y into qkv Q region (safe: this block's Q rows already in regs;
        // other blocks of same bh own disjoint q-tiles; K/V regions untouched)
#pragma unroll
        for (int r = 0; r < 4; ++r) {
            int t = q0 + 16 * wave + 4 * g + r;
            float inv = 1.0f / l_r[r];
            size_t rowoff = (rowb + t) * 2304 + qcol;
#pragma unroll
            for (int c = 0; c < 6; ++c)
                qkv[rowoff + 16 * c + lr] = f2bf(o[c][r] * inv);
        }
        __syncthreads();
    }
}

// ---------------- GEMM2: out = Y @ w_proj + b_proj (fp32 out), A = qkv cols 0..767 ----------------

__global__ __launch_bounds__(256) void k_gemm_out(const u16* __restrict__ A,   // qkv, stride 2304
                                                  const u16* __restrict__ BT,  // [768][768]
                                                  const float* __restrict__ bias,
                                                  float* __restrict__ out) {
    __shared__ __align__(16) u16 lds[2 * 16384];
    const int tid = threadIdx.x;
    int id = blockIdx.x;                        // 384 blocks
    int nid = (id & 7) * 48 + (id >> 3);        // XCD-chunked remap (384 % 8 == 0)
    int by = nid / 6, bx = nid - by * 6;
    const int m0 = by * 128, n0 = bx * 128;

    f32x4 acc[4][4];
#pragma unroll
    for (int i = 0; i < 4; ++i)
#pragma unroll
        for (int j = 0; j < 4; ++j) acc[i][j] = (f32x4){0.f, 0.f, 0.f, 0.f};

    gemm_core_128_db(A + (size_t)m0 * 2304, 2304, BT + (size_t)n0 * 768, lds, tid, acc);

    const int lane = tid & 63, wave = tid >> 6;
    const int wr = wave >> 1, wc = wave & 1;
    const int g = lane >> 4, lr = lane & 15;
#pragma unroll
    for (int i = 0; i < 4; ++i) {
        int row = m0 + 64 * wr + 16 * i + 4 * g;
#pragma unroll
        for (int j = 0; j < 4; ++j) {
            int col = n0 + 64 * wc + 16 * j + lr;
            float bsv = bias[col];
#pragma unroll
            for (int r = 0; r < 4; ++r)
                out[(size_t)(row + r) * 768 + col] = acc[i][j][r] + bsv;
        }
    }
}

// ---------------- launch ----------------

extern "C" void kernel_launch(void* const* d_in, const int* in_sizes, int n_in,
                              void* d_out, int out_size, void* d_ws, size_t ws_size,
                              hipStream_t stream) {
    const float* x      = (const float*)d_in[0];
    const float* w_qkv  = (const float*)d_in[1];
    const float* b_qkv  = (const float*)d_in[2];
    const float* w_proj = (const float*)d_in[3];
    const float* b_proj = (const float*)d_in[4];
    float* out = (float*)d_out;

    u16* xb    = (u16*)d_ws;            // 6291456
    u16* wqkvT = xb + 6291456;          // 1769472
    u16* wpT   = wqkvT + 1769472;       // 589824
    u16* qkv   = wpT + 589824;          // 18874368  [8192][2304]
    u16* Vtg   = qkv + 18874368;        // 6291456   [bh][96][1024]

    hipFuncSetAttribute((const void*)k_attn,
                        hipFuncAttributeMaxDynamicSharedMemorySize, 69632);

    k_cvt_x<<<6144, 256, 0, stream>>>(x, xb, 6291456);
    k_cvt_T<<<dim3(36, 12), 256, 0, stream>>>(w_qkv, wqkvT, 768, 2304);
    k_cvt_T<<<dim3(12, 12), 256, 0, stream>>>(w_proj, wpT, 768, 768);
    k_gemm_qkv<<<1152, 256, 0, stream>>>(xb, wqkvT, b_qkv, qkv);
    k_vT<<<dim3(16, 64), 256, 0, stream>>>(qkv, Vtg);
    k_attn<<<dim3(8, 64), 256, 69632, stream>>>(qkv, Vtg);
    k_gemm_out<<<384, 256, 0, stream>>>(qkv, wpT, b_proj, out);
}